// Round 4
// baseline (509.398 us; speedup 1.0000x reference)
//
#include <hip/hip_runtime.h>

#define BB 64
#define TT 512
#define NN 48
#define PP 16

typedef float f4 __attribute__((ext_vector_type(4)));
typedef short s8v __attribute__((ext_vector_type(8)));
typedef int i4v __attribute__((ext_vector_type(4)));

// bf16 round-to-nearest-even, manual (avoids __hip_bfloat162 bit_cast issues)
__device__ __forceinline__ unsigned f2bf_bits(float x) {
    unsigned u = __builtin_bit_cast(unsigned, x);
    return (u + 0x7fffu + ((u >> 16) & 1u)) >> 16;
}
__device__ __forceinline__ int pk_bf16(float a, float b) {
    return (int)(f2bf_bits(a) | (f2bf_bits(b) << 16));
}
__device__ __forceinline__ float wsum(float v) {
#pragma unroll
    for (int k = 32; k >= 1; k >>= 1) v += __shfl_xor(v, k, 64);
    return v;
}

// Per-wave batched CRF denominator: 16 sequences (seq = lane&15), uniform length.
// Linear-space recurrence u' = (u · E) ⊙ exp(em), E = exp(trans) in bf16 MFMA A-frags
// (Eᵀ tiles, K zero-padded past 48). State u lives in B-frags (bf16); per-step D→B
// transpose via wave-private LDS rows of 144 B (bytes [96,144) pre-zeroed => free
// K-tail zeros). RP = rescale period (power of 2; exact pow2 rescale, no log/exp).
template <int RP>
__device__ __forceinline__ float den16(const float* __restrict__ rowbase, int estride,
                                       int steps, const s8v (&AE)[3][2],
                                       char* __restrict__ ltr) {
    const int lane = threadIdx.x & 63;
    const int seq = lane & 15, quad = lane >> 4;

    // ---- u0 = exp(first emission), loaded directly in B-layout ----
    // B[k][n]: n = seq, k = quad*8 + j (B0), 32 + quad*8 + j (B1).
    // Quads 2,3 of B1 would be k=48..63: they duplicate states 32..47 here, but
    // the A-fragments are zero for those k, so the products vanish.
    float4 ua = ((const float4*)(rowbase + quad * 8))[0];
    float4 ub = ((const float4*)(rowbase + quad * 8))[1];
    float4 uc = ((const float4*)(rowbase + 32 + (quad & 1) * 8))[0];
    float4 ud = ((const float4*)(rowbase + 32 + (quad & 1) * 8))[1];
    float u0[16] = {ua.x, ua.y, ua.z, ua.w, ub.x, ub.y, ub.z, ub.w,
                    uc.x, uc.y, uc.z, uc.w, ud.x, ud.y, ud.z, ud.w};
#pragma unroll
    for (int i = 0; i < 16; ++i) u0[i] = __expf(u0[i]);
    i4v bi0 = {pk_bf16(u0[0], u0[1]), pk_bf16(u0[2], u0[3]),
               pk_bf16(u0[4], u0[5]), pk_bf16(u0[6], u0[7])};
    i4v bi1 = {pk_bf16(u0[8], u0[9]), pk_bf16(u0[10], u0[11]),
               pk_bf16(u0[12], u0[13]), pk_bf16(u0[14], u0[15])};
    s8v B0 = __builtin_bit_cast(s8v, bi0);
    s8v B1 = __builtin_bit_cast(s8v, bi1);

    const f4 Z = {0.f, 0.f, 0.f, 0.f};
    f4 D0 = Z, D1 = Z, D2 = Z;
    int Cexp = 0;
    char* wrow = ltr + seq * 144;

    // emissions for step 1 (prefetched one step ahead inside the loop)
    const float* emb = rowbase + quad * 4 + estride;
    float em[12];
    {
        float4 a = ((const float4*)emb)[0];
        float4 b = ((const float4*)(emb + 16))[0];
        float4 c = ((const float4*)(emb + 32))[0];
        em[0] = a.x; em[1] = a.y; em[2] = a.z; em[3] = a.w;
        em[4] = b.x; em[5] = b.y; em[6] = b.z; em[7] = b.w;
        em[8] = c.x; em[9] = c.y; em[10] = c.z; em[11] = c.w;
    }

    for (int s = 1;; ++s) {
        // issue next-step emission loads early (latency hidden behind MFMA+LDS)
        const float* embn = emb + (s < steps ? estride : 0);
        float4 na = ((const float4*)embn)[0];
        float4 nb = ((const float4*)(embn + 16))[0];
        float4 nc = ((const float4*)(embn + 32))[0];

        D0 = __builtin_amdgcn_mfma_f32_16x16x32_bf16(AE[0][1], B1, Z, 0, 0, 0);
        D0 = __builtin_amdgcn_mfma_f32_16x16x32_bf16(AE[0][0], B0, D0, 0, 0, 0);
        D1 = __builtin_amdgcn_mfma_f32_16x16x32_bf16(AE[1][1], B1, Z, 0, 0, 0);
        D1 = __builtin_amdgcn_mfma_f32_16x16x32_bf16(AE[1][0], B0, D1, 0, 0, 0);
        D2 = __builtin_amdgcn_mfma_f32_16x16x32_bf16(AE[2][1], B1, Z, 0, 0, 0);
        D2 = __builtin_amdgcn_mfma_f32_16x16x32_bf16(AE[2][0], B0, D2, 0, 0, 0);

        D0[0] *= __expf(em[0]); D0[1] *= __expf(em[1]);
        D0[2] *= __expf(em[2]); D0[3] *= __expf(em[3]);
        D1[0] *= __expf(em[4]); D1[1] *= __expf(em[5]);
        D1[2] *= __expf(em[6]); D1[3] *= __expf(em[7]);
        D2[0] *= __expf(em[8]); D2[1] *= __expf(em[9]);
        D2[2] *= __expf(em[10]); D2[3] *= __expf(em[11]);

        if (s == steps) break;

        if ((s & (RP - 1)) == 0) {
            float S = ((D0[0] + D0[1]) + (D0[2] + D0[3])) +
                      ((D1[0] + D1[1]) + (D1[2] + D1[3])) +
                      ((D2[0] + D2[1]) + (D2[2] + D2[3]));
            S += __shfl_xor(S, 16, 64);
            S += __shfl_xor(S, 32, 64);
            int e = (__builtin_bit_cast(int, S) >> 23) - 127;
            float scl = __builtin_bit_cast(float, (127 - e) << 23);
            Cexp += e;
#pragma unroll
            for (int r = 0; r < 4; ++r) { D0[r] *= scl; D1[r] *= scl; D2[r] *= scl; }
        }

        // pack to bf16 and transpose D-layout -> B-layout via this wave's LDS rows
        *(int2*)(wrow + 0 * 32 + quad * 8) = make_int2(pk_bf16(D0[0], D0[1]), pk_bf16(D0[2], D0[3]));
        *(int2*)(wrow + 1 * 32 + quad * 8) = make_int2(pk_bf16(D1[0], D1[1]), pk_bf16(D1[2], D1[3]));
        *(int2*)(wrow + 2 * 32 + quad * 8) = make_int2(pk_bf16(D2[0], D2[1]), pk_bf16(D2[2], D2[3]));
        B0 = *(const s8v*)(wrow + quad * 16);
        B1 = *(const s8v*)(wrow + 64 + quad * 16);

        em[0] = na.x; em[1] = na.y; em[2] = na.z; em[3] = na.w;
        em[4] = nb.x; em[5] = nb.y; em[6] = nb.z; em[7] = nb.w;
        em[8] = nc.x; em[9] = nc.y; em[10] = nc.z; em[11] = nc.w;
        emb = embn;
    }

    float S = ((D0[0] + D0[1]) + (D0[2] + D0[3])) +
              ((D1[0] + D1[1]) + (D1[2] + D1[3])) +
              ((D2[0] + D2[1]) + (D2[2] + D2[3]));
    S += __shfl_xor(S, 16, 64);
    S += __shfl_xor(S, 32, 64);
    return __logf(S) + (float)Cexp * 0.6931471805599453f;
}

// Length-1 sequences: log-denominator = logsumexp of the single emission row.
__device__ __forceinline__ float den0(const float* __restrict__ rowbase) {
    const int lane = threadIdx.x & 63;
    const int quad = lane >> 4;
    float4 ua = ((const float4*)(rowbase + quad * 8))[0];
    float4 ub = ((const float4*)(rowbase + quad * 8))[1];
    float4 uc = ((const float4*)(rowbase + 32 + (quad & 1) * 8))[0];
    float4 ud = ((const float4*)(rowbase + 32 + (quad & 1) * 8))[1];
    float S = (__expf(ua.x) + __expf(ua.y) + __expf(ua.z) + __expf(ua.w)) +
              (__expf(ub.x) + __expf(ub.y) + __expf(ub.z) + __expf(ub.w));
    float S1 = (__expf(uc.x) + __expf(uc.y) + __expf(uc.z) + __expf(uc.w)) +
               (__expf(ud.x) + __expf(ud.y) + __expf(ud.z) + __expf(ud.w));
    if (quad >= 2) S1 = 0.f;  // quads 2,3 duplicate states 32..47
    S += S1;
    S += __shfl_xor(S, 16, 64);
    S += __shfl_xor(S, 32, 64);
    return __logf(S);
}

__global__ void zero_out(float* out) {
    if (threadIdx.x < 3) out[threadIdx.x] = 0.f;
}

// Block roles: [0,16) = T (64 waves, 16 seqs/wave, 496..511 steps),
//              [16,528) = L (2048 waves), [528,1040) = R (2048 waves).
// Each wave batches 16 b-values at fixed p (T) or fixed t (L/R) => uniform length.
__global__ __launch_bounds__(256) void crf_all(const float* __restrict__ logits,
                                               const float* __restrict__ transT,
                                               const float* __restrict__ transL,
                                               const float* __restrict__ transR,
                                               const int* __restrict__ tags,
                                               float* __restrict__ out) {
    __shared__ float s_trans[NN * NN];
    __shared__ i4v s_tr4[4][144];  // 4 waves x (16 rows x 144 B)
    __shared__ float s_acc;
    const int tid = threadIdx.x, bid = blockIdx.x;
    const int lane = tid & 63, widx = tid >> 6;
    const int seq = lane & 15, quad = lane >> 4;

    int role;
    const float* tr;
    if (bid < 16) { role = 0; tr = transT; }
    else if (bid < 528) { role = 1; tr = transL; }
    else { role = 2; tr = transR; }

    if (tid == 0) s_acc = 0.f;
    for (int i = tid; i < NN * NN; i += 256) s_trans[i] = tr[i];
    __syncthreads();

    char* ltr = (char*)s_tr4[widx];
    // zero this wave's row tail bytes [96,144) once (provides K=48..63 zeros)
    if (quad < 3) *(i4v*)(ltr + seq * 144 + 96 + quad * 16) = i4v{0, 0, 0, 0};

    // ---- build static Eᵀ A-frags: A[m=j-state][k=i-state] = exp(trans[i][j]), 0 for k>=48
    s8v AE[3][2];
#pragma unroll
    for (int tile = 0; tile < 3; ++tile)
#pragma unroll
        for (int c = 0; c < 2; ++c) {
            int vals[4];
#pragma unroll
            for (int r = 0; r < 4; ++r) {
                int i0 = c * 32 + quad * 8 + 2 * r;
                float e0 = (i0 < NN) ? __expf(s_trans[i0 * NN + tile * 16 + seq]) : 0.f;
                float e1 = (i0 + 1 < NN) ? __expf(s_trans[(i0 + 1) * NN + tile * 16 + seq]) : 0.f;
                vals[r] = pk_bf16(e0, e1);
            }
            i4v t4 = {vals[0], vals[1], vals[2], vals[3]};
            AE[tile][c] = __builtin_bit_cast(s8v, t4);
        }

    float ld = 0.f, sc = 0.f;
    if (role == 0) {
        // ---- T: wave w: p = w>>2, b0 = (w&3)*16; length 512-p
        int w = bid * 4 + widx;
        int p = w >> 2, b0 = (w & 3) * 16;
        int steps = (TT - 1) - p;
        const float* rowbase = logits + (size_t)(p * BB + b0 + seq) * (TT * NN);
        ld = den16<4>(rowbase, NN, steps, AE, ltr);
        // numerator: lanes = (seq sq, time-phase tc)
        int sq = lane >> 2, tc = lane & 3;
        int Ls = TT - p;
        const float* lgs = logits + (size_t)(p * BB + b0 + sq) * (TT * NN);
        const int* tgs = tags + (size_t)(p * BB + b0 + sq) * TT;
        for (int t = tc; t < Ls; t += 4) {
            int tg = tgs[t];
            float e = lgs[t * NN + tg];
            float tsc = (t >= 1) ? s_trans[tgs[t - 1] * NN + tg] : 0.f;
            sc += e + tsc;
        }
    } else if (role == 1) {
        // ---- L: wave w: t = w>>2, b0 = (w&3)*16; length min(512-t,16); stride = p-stride
        int w = (bid - 16) * 4 + widx;
        int t = w >> 2, b0 = (w & 3) * 16;
        int Lh = min(TT - t, PP), steps = Lh - 1;
        const float* rowbase = logits + (size_t)(b0 + seq) * (TT * NN) + t * NN;
        if (steps > 0) ld = den16<8>(rowbase, BB * TT * NN, steps, AE, ltr);
        else ld = den0(rowbase);
        int sq = lane >> 2, pc = lane & 3;
        int bq = b0 + sq;
        for (int p2 = pc; p2 < Lh; p2 += 4) {
            int idx = (p2 * BB + bq) * TT + t;
            int tg = tags[idx];
            sc += logits[(size_t)idx * NN + tg];
            if (p2 >= 1) sc += s_trans[tags[idx - BB * TT] * NN + tg];
        }
    } else {
        // ---- R: wave w: t = w>>2; length min(t+1,16); element p at logits[p,b,t-p]
        int w = (bid - 528) * 4 + widx;
        int t = w >> 2, b0 = (w & 3) * 16;
        int Lh = min(t + 1, PP), steps = Lh - 1;
        const float* rowbase = logits + (size_t)(b0 + seq) * (TT * NN) + t * NN;
        if (steps > 0) ld = den16<8>(rowbase, BB * TT * NN - NN, steps, AE, ltr);
        else ld = den0(rowbase);
        int sq = lane >> 2, pc = lane & 3;
        int bq = b0 + sq;
        for (int p2 = pc; p2 < Lh; p2 += 4) {
            int idx = (p2 * BB + bq) * TT + (t - p2);
            int tg = tags[idx];
            sc += logits[(size_t)idx * NN + tg];
            if (p2 >= 1) sc += s_trans[tags[((p2 - 1) * BB + bq) * TT + (t - p2 + 1)] * NN + tg];
        }
    }

    // ld is replicated across the 4 quads of each seq — count quad 0 only
    float contrib = ((quad == 0) ? ld : 0.f) - sc;
    contrib = wsum(contrib);
    if (lane == 0) atomicAdd(&s_acc, contrib);
    __syncthreads();
    if (tid == 0) atomicAdd(&out[role], s_acc);
}

extern "C" void kernel_launch(void* const* d_in, const int* in_sizes, int n_in,
                              void* d_out, int out_size, void* d_ws, size_t ws_size,
                              hipStream_t stream) {
    const float* logits = (const float*)d_in[0];
    const float* trans_T = (const float*)d_in[1];
    const float* trans_L = (const float*)d_in[2];
    const float* trans_R = (const float*)d_in[3];
    const int* tags = (const int*)d_in[4];
    float* out = (float*)d_out;

    hipLaunchKernelGGL(zero_out, dim3(1), dim3(64), 0, stream, out);
    hipLaunchKernelGGL(crf_all, dim3(1040), dim3(256), 0, stream,
                       logits, trans_T, trans_L, trans_R, tags, out);
}

// Round 5
// 479.233 us; speedup vs baseline: 1.0629x; 1.0629x over previous
//
#include <hip/hip_runtime.h>

#define BB 64
#define TT 512
#define NN 48
#define PP 16

typedef float f4 __attribute__((ext_vector_type(4)));
typedef short s8v __attribute__((ext_vector_type(8)));
typedef int i4v __attribute__((ext_vector_type(4)));

// bf16 round-to-nearest-even, manual (avoids __hip_bfloat162 bit_cast issues)
__device__ __forceinline__ unsigned f2bf_bits(float x) {
    unsigned u = __builtin_bit_cast(unsigned, x);
    return (u + 0x7fffu + ((u >> 16) & 1u)) >> 16;
}
__device__ __forceinline__ int pk_bf16(float a, float b) {
    return (int)(f2bf_bits(a) | (f2bf_bits(b) << 16));
}
__device__ __forceinline__ float wsum(float v) {
#pragma unroll
    for (int k = 32; k >= 1; k >>= 1) v += __shfl_xor(v, k, 64);
    return v;
}

// ---------------------------------------------------------------------------
// Batched CRF denominator: 16 sequences per wave (seq = lane&15), uniform len.
// Linear space: u' = (u·E) ⊙ exp(em). State permutation σ on the MFMA K axis:
//   B0 slot k=q*8+j : j<4 -> state q*4+j ; j>=4 -> state 16+q*4+(j-4)
//   B1 slot k=32+q*8+j : j<4 -> state 32+q*4+j ; j>=4 -> dead (zero)
// With this σ, the D fragment (states quad*4+r per tile) packs DIRECTLY into
// the next step's B fragments — no LDS/transpose on the critical path.
// 4-deep emission prefetch ring hides L3/HBM latency.
// RP = rescale period (power of 2; exact pow2 rescale, integer exponent acc).
// ---------------------------------------------------------------------------
template <int RP>
__device__ __forceinline__ float den16(const float* __restrict__ rowbase, int estride,
                                       int steps, const s8v (&A)[3][2]) {
    const int lane = threadIdx.x & 63;
    const int quad = lane >> 4;
    const float* p0 = rowbase + quad * 4;
    const f4 Z = {0.f, 0.f, 0.f, 0.f};

    // ---- u0 = exp(emissions at step 0), loaded directly in σ-B-layout ----
    float4 ua = *(const float4*)(p0);
    float4 ub = *(const float4*)(p0 + 16);
    float4 uc = *(const float4*)(p0 + 32);
    i4v b0i = {pk_bf16(__expf(ua.x), __expf(ua.y)), pk_bf16(__expf(ua.z), __expf(ua.w)),
               pk_bf16(__expf(ub.x), __expf(ub.y)), pk_bf16(__expf(ub.z), __expf(ub.w))};
    i4v b1i = {pk_bf16(__expf(uc.x), __expf(uc.y)), pk_bf16(__expf(uc.z), __expf(uc.w)), 0, 0};
    s8v B0 = __builtin_bit_cast(s8v, b0i);
    s8v B1 = __builtin_bit_cast(s8v, b1i);

    f4 D0 = Z, D1 = Z, D2 = Z;
    int Cexp = 0;
    int s = 1;

    // ---- 4-deep emission prefetch ring (addresses clamped to last step) ----
    float4 r0[3], r1[3], r2[3], r3[3];
#define EMLOAD(R, S)                                                             \
    do {                                                                         \
        int cl_ = (S) < steps ? (S) : steps;                                     \
        const float* q_ = p0 + (size_t)cl_ * (size_t)estride;                    \
        R[0] = *(const float4*)q_;                                               \
        R[1] = *(const float4*)(q_ + 16);                                        \
        R[2] = *(const float4*)(q_ + 32);                                        \
    } while (0)

    EMLOAD(r0, 1); EMLOAD(r1, 2); EMLOAD(r2, 3); EMLOAD(r3, 4);

#define DOSTEP(R)                                                                \
    do {                                                                         \
        D0 = __builtin_amdgcn_mfma_f32_16x16x32_bf16(A[0][1], B1, Z, 0, 0, 0);   \
        D0 = __builtin_amdgcn_mfma_f32_16x16x32_bf16(A[0][0], B0, D0, 0, 0, 0);  \
        D1 = __builtin_amdgcn_mfma_f32_16x16x32_bf16(A[1][1], B1, Z, 0, 0, 0);   \
        D1 = __builtin_amdgcn_mfma_f32_16x16x32_bf16(A[1][0], B0, D1, 0, 0, 0);  \
        D2 = __builtin_amdgcn_mfma_f32_16x16x32_bf16(A[2][1], B1, Z, 0, 0, 0);   \
        D2 = __builtin_amdgcn_mfma_f32_16x16x32_bf16(A[2][0], B0, D2, 0, 0, 0);  \
        D0[0] *= __expf(R[0].x); D0[1] *= __expf(R[0].y);                        \
        D0[2] *= __expf(R[0].z); D0[3] *= __expf(R[0].w);                        \
        D1[0] *= __expf(R[1].x); D1[1] *= __expf(R[1].y);                        \
        D1[2] *= __expf(R[1].z); D1[3] *= __expf(R[1].w);                        \
        D2[0] *= __expf(R[2].x); D2[1] *= __expf(R[2].y);                        \
        D2[2] *= __expf(R[2].z); D2[3] *= __expf(R[2].w);                        \
    } while (0)

#define REPACK()                                                                 \
    do {                                                                         \
        if ((s & (RP - 1)) == 0) {                                               \
            float Sx = ((D0[0] + D0[1]) + (D0[2] + D0[3])) +                     \
                       ((D1[0] + D1[1]) + (D1[2] + D1[3])) +                     \
                       ((D2[0] + D2[1]) + (D2[2] + D2[3]));                      \
            Sx += __shfl_xor(Sx, 16, 64);                                        \
            Sx += __shfl_xor(Sx, 32, 64);                                        \
            int e_ = (__builtin_bit_cast(int, Sx) >> 23) - 127;                  \
            float scl_ = __builtin_bit_cast(float, (127 - e_) << 23);            \
            Cexp += e_;                                                          \
            D0 *= scl_; D1 *= scl_; D2 *= scl_;                                  \
        }                                                                        \
        i4v nb0 = {pk_bf16(D0[0], D0[1]), pk_bf16(D0[2], D0[3]),                 \
                   pk_bf16(D1[0], D1[1]), pk_bf16(D1[2], D1[3])};                \
        i4v nb1 = {pk_bf16(D2[0], D2[1]), pk_bf16(D2[2], D2[3]), 0, 0};          \
        B0 = __builtin_bit_cast(s8v, nb0);                                       \
        B1 = __builtin_bit_cast(s8v, nb1);                                       \
    } while (0)

    for (;;) {
        DOSTEP(r0); if (s == steps) break; REPACK(); EMLOAD(r0, s + 4); ++s;
        DOSTEP(r1); if (s == steps) break; REPACK(); EMLOAD(r1, s + 4); ++s;
        DOSTEP(r2); if (s == steps) break; REPACK(); EMLOAD(r2, s + 4); ++s;
        DOSTEP(r3); if (s == steps) break; REPACK(); EMLOAD(r3, s + 4); ++s;
    }
#undef EMLOAD
#undef DOSTEP
#undef REPACK

    float S = ((D0[0] + D0[1]) + (D0[2] + D0[3])) +
              ((D1[0] + D1[1]) + (D1[2] + D1[3])) +
              ((D2[0] + D2[1]) + (D2[2] + D2[3]));
    S += __shfl_xor(S, 16, 64);
    S += __shfl_xor(S, 32, 64);
    return __logf(S) + (float)Cexp * 0.6931471805599453f;
}

// Length-1 sequences: log-denominator = logsumexp of the single emission row.
__device__ __forceinline__ float den0(const float* __restrict__ rowbase) {
    const int lane = threadIdx.x & 63;
    const int quad = lane >> 4;
    const float* p0 = rowbase + quad * 4;
    float4 ua = *(const float4*)(p0);
    float4 ub = *(const float4*)(p0 + 16);
    float4 uc = *(const float4*)(p0 + 32);
    float S = (__expf(ua.x) + __expf(ua.y) + __expf(ua.z) + __expf(ua.w)) +
              (__expf(ub.x) + __expf(ub.y) + __expf(ub.z) + __expf(ub.w)) +
              (__expf(uc.x) + __expf(uc.y) + __expf(uc.z) + __expf(uc.w));
    S += __shfl_xor(S, 16, 64);
    S += __shfl_xor(S, 32, 64);
    return __logf(S);
}

__global__ void zero_out(float* out) {
    if (threadIdx.x < 3) out[threadIdx.x] = 0.f;
}

// Block roles: [0,16) = T (64 waves, 16 seqs/wave, 496..511 steps),
//              [16,528) = L (2048 waves), [528,1040) = R (2048 waves).
__global__ __launch_bounds__(256) void crf_all(const float* __restrict__ logits,
                                               const float* __restrict__ transT,
                                               const float* __restrict__ transL,
                                               const float* __restrict__ transR,
                                               const int* __restrict__ tags,
                                               float* __restrict__ out) {
    __shared__ float s_trans[NN * NN];
    __shared__ float s_acc;
    const int tid = threadIdx.x, bid = blockIdx.x;
    const int lane = tid & 63, widx = tid >> 6;
    const int quad = lane >> 4;

    int role;
    const float* tr;
    if (bid < 16) { role = 0; tr = transT; }
    else if (bid < 528) { role = 1; tr = transL; }
    else { role = 2; tr = transR; }

    if (tid == 0) s_acc = 0.f;
    for (int i = tid; i < NN * NN; i += 256) s_trans[i] = tr[i];
    __syncthreads();

    // ---- build σ-permuted Eᵀ A-frags: A[m][k] = exp(trans[σ(k)][t*16+m]) ----
    s8v A[3][2];
    {
        int m = lane & 15;
#pragma unroll
        for (int t = 0; t < 3; ++t) {
            int col = t * 16 + m;
            // k slots j=0..3 -> states quad*4+j ; j=4..7 -> 16+quad*4+(j-4)
            i4v v0 = {pk_bf16(__expf(s_trans[(quad * 4 + 0) * NN + col]),
                              __expf(s_trans[(quad * 4 + 1) * NN + col])),
                      pk_bf16(__expf(s_trans[(quad * 4 + 2) * NN + col]),
                              __expf(s_trans[(quad * 4 + 3) * NN + col])),
                      pk_bf16(__expf(s_trans[(16 + quad * 4 + 0) * NN + col]),
                              __expf(s_trans[(16 + quad * 4 + 1) * NN + col])),
                      pk_bf16(__expf(s_trans[(16 + quad * 4 + 2) * NN + col]),
                              __expf(s_trans[(16 + quad * 4 + 3) * NN + col]))};
            i4v v1 = {pk_bf16(__expf(s_trans[(32 + quad * 4 + 0) * NN + col]),
                              __expf(s_trans[(32 + quad * 4 + 1) * NN + col])),
                      pk_bf16(__expf(s_trans[(32 + quad * 4 + 2) * NN + col]),
                              __expf(s_trans[(32 + quad * 4 + 3) * NN + col])),
                      0, 0};
            A[t][0] = __builtin_bit_cast(s8v, v0);
            A[t][1] = __builtin_bit_cast(s8v, v1);
        }
    }

    const int seq = lane & 15;
    float ld = 0.f, sc = 0.f;
    if (role == 0) {
        // ---- T: wave w: p = w>>2, b0 = (w&3)*16; length 512-p
        int w = bid * 4 + widx;
        int p = w >> 2, b0 = (w & 3) * 16;
        int steps = (TT - 1) - p;
        const float* rowbase = logits + (size_t)(p * BB + b0 + seq) * (TT * NN);
        ld = den16<4>(rowbase, NN, steps, A);
        // numerator: lanes = (seq sq, time-phase tc)
        int sq = lane >> 2, tc = lane & 3;
        int Ls = TT - p;
        const float* lgs = logits + (size_t)(p * BB + b0 + sq) * (TT * NN);
        const int* tgs = tags + (size_t)(p * BB + b0 + sq) * TT;
        for (int t = tc; t < Ls; t += 4) {
            int tg = tgs[t];
            float e = lgs[t * NN + tg];
            float tsc = (t >= 1) ? s_trans[tgs[t - 1] * NN + tg] : 0.f;
            sc += e + tsc;
        }
    } else if (role == 1) {
        // ---- L: wave w: t = w>>2, b0 = (w&3)*16; length min(512-t,16)
        int w = (bid - 16) * 4 + widx;
        int t = w >> 2, b0 = (w & 3) * 16;
        int Lh = min(TT - t, PP), steps = Lh - 1;
        const float* rowbase = logits + (size_t)(b0 + seq) * (TT * NN) + t * NN;
        if (steps > 0) ld = den16<8>(rowbase, BB * TT * NN, steps, A);
        else ld = den0(rowbase);
        int sq = lane >> 2, pc = lane & 3;
        int bq = b0 + sq;
        for (int p2 = pc; p2 < Lh; p2 += 4) {
            int idx = (p2 * BB + bq) * TT + t;
            int tg = tags[idx];
            sc += logits[(size_t)idx * NN + tg];
            if (p2 >= 1) sc += s_trans[tags[idx - BB * TT] * NN + tg];
        }
    } else {
        // ---- R: wave w: t = w>>2; length min(t+1,16); element p at logits[p,b,t-p]
        int w = (bid - 528) * 4 + widx;
        int t = w >> 2, b0 = (w & 3) * 16;
        int Lh = min(t + 1, PP), steps = Lh - 1;
        const float* rowbase = logits + (size_t)(b0 + seq) * (TT * NN) + t * NN;
        if (steps > 0) ld = den16<8>(rowbase, BB * TT * NN - NN, steps, A);
        else ld = den0(rowbase);
        int sq = lane >> 2, pc = lane & 3;
        int bq = b0 + sq;
        for (int p2 = pc; p2 < Lh; p2 += 4) {
            int idx = (p2 * BB + bq) * TT + (t - p2);
            int tg = tags[idx];
            sc += logits[(size_t)idx * NN + tg];
            if (p2 >= 1) sc += s_trans[tags[((p2 - 1) * BB + bq) * TT + (t - p2 + 1)] * NN + tg];
        }
    }

    // ld is replicated across the 4 quads of each seq — count quad 0 only
    float contrib = ((quad == 0) ? ld : 0.f) - sc;
    contrib = wsum(contrib);
    if (lane == 0) atomicAdd(&s_acc, contrib);
    __syncthreads();
    if (tid == 0) atomicAdd(&out[role], s_acc);
}

extern "C" void kernel_launch(void* const* d_in, const int* in_sizes, int n_in,
                              void* d_out, int out_size, void* d_ws, size_t ws_size,
                              hipStream_t stream) {
    const float* logits = (const float*)d_in[0];
    const float* trans_T = (const float*)d_in[1];
    const float* trans_L = (const float*)d_in[2];
    const float* trans_R = (const float*)d_in[3];
    const int* tags = (const int*)d_in[4];
    float* out = (float*)d_out;

    hipLaunchKernelGGL(zero_out, dim3(1), dim3(64), 0, stream, out);
    hipLaunchKernelGGL(crf_all, dim3(1040), dim3(256), 0, stream,
                       logits, trans_T, trans_L, trans_R, tags, out);
}

// Round 6
// 386.889 us; speedup vs baseline: 1.3167x; 1.2387x over previous
//
#include <hip/hip_runtime.h>

#define BB 64
#define TT 512
#define NN 48
#define PP 16

typedef float f4 __attribute__((ext_vector_type(4)));
typedef short s8v __attribute__((ext_vector_type(8)));
typedef int i4v __attribute__((ext_vector_type(4)));

// bf16 round-to-nearest-even, manual (avoids __hip_bfloat162 bit_cast issues)
__device__ __forceinline__ unsigned f2bf_bits(float x) {
    unsigned u = __builtin_bit_cast(unsigned, x);
    return (u + 0x7fffu + ((u >> 16) & 1u)) >> 16;
}
__device__ __forceinline__ int pk_bf16(float a, float b) {
    return (int)(f2bf_bits(a) | (f2bf_bits(b) << 16));
}
__device__ __forceinline__ float wsum(float v) {
#pragma unroll
    for (int k = 32; k >= 1; k >>= 1) v += __shfl_xor(v, k, 64);
    return v;
}

// ---------------------------------------------------------------------------
// Batched CRF denominator: 16 sequences per wave (seq = lane&15), uniform len.
// Linear space: u' = (u·E) ⊙ exp(em). State permutation σ on the MFMA K axis:
//   B0 slot k=q*8+j : j<4 -> state q*4+j ; j>=4 -> state 16+q*4+(j-4)
//   B1 slot k=32+q*8+j : j<4 -> state 32+q*4+j ; j>=4 -> dead (zero)
// With σ, the D fragment packs DIRECTLY into the next B fragments (no LDS).
// DEPTH-deep emission prefetch ring (DEPTH*3 float4 in flight per lane) hides
// HBM/L3 latency; RP = pow2 rescale period (exact, integer exponent acc).
// ---------------------------------------------------------------------------
template <int RP, int DEPTH>
__device__ __forceinline__ float den16(const float* __restrict__ rowbase, int estride,
                                       int steps, const s8v (&A)[3][2]) {
    const int lane = threadIdx.x & 63;
    const int quad = lane >> 4;
    const float* p0 = rowbase + quad * 4;
    const f4 Z = {0.f, 0.f, 0.f, 0.f};

    // ---- u0 = exp(emissions at step 0), loaded directly in σ-B-layout ----
    float4 ua = *(const float4*)(p0);
    float4 ub = *(const float4*)(p0 + 16);
    float4 uc = *(const float4*)(p0 + 32);
    i4v b0i = {pk_bf16(__expf(ua.x), __expf(ua.y)), pk_bf16(__expf(ua.z), __expf(ua.w)),
               pk_bf16(__expf(ub.x), __expf(ub.y)), pk_bf16(__expf(ub.z), __expf(ub.w))};
    i4v b1i = {pk_bf16(__expf(uc.x), __expf(uc.y)), pk_bf16(__expf(uc.z), __expf(uc.w)), 0, 0};
    s8v B0 = __builtin_bit_cast(s8v, b0i);
    s8v B1 = __builtin_bit_cast(s8v, b1i);

    f4 D0 = Z, D1 = Z, D2 = Z;
    int Cexp = 0;

    float4 r[DEPTH][3];
    auto emload = [&](int d, int S) {
        int cl = S < steps ? S : steps;  // clamp: duplicate last row (L2-hit, harmless)
        const float* q = p0 + (size_t)cl * (size_t)estride;
        r[d][0] = *(const float4*)q;
        r[d][1] = *(const float4*)(q + 16);
        r[d][2] = *(const float4*)(q + 32);
    };
    auto dostep = [&](const float4(&R)[3]) {
        D0 = __builtin_amdgcn_mfma_f32_16x16x32_bf16(A[0][1], B1, Z, 0, 0, 0);
        D0 = __builtin_amdgcn_mfma_f32_16x16x32_bf16(A[0][0], B0, D0, 0, 0, 0);
        D1 = __builtin_amdgcn_mfma_f32_16x16x32_bf16(A[1][1], B1, Z, 0, 0, 0);
        D1 = __builtin_amdgcn_mfma_f32_16x16x32_bf16(A[1][0], B0, D1, 0, 0, 0);
        D2 = __builtin_amdgcn_mfma_f32_16x16x32_bf16(A[2][1], B1, Z, 0, 0, 0);
        D2 = __builtin_amdgcn_mfma_f32_16x16x32_bf16(A[2][0], B0, D2, 0, 0, 0);
        D0[0] *= __expf(R[0].x); D0[1] *= __expf(R[0].y);
        D0[2] *= __expf(R[0].z); D0[3] *= __expf(R[0].w);
        D1[0] *= __expf(R[1].x); D1[1] *= __expf(R[1].y);
        D1[2] *= __expf(R[1].z); D1[3] *= __expf(R[1].w);
        D2[0] *= __expf(R[2].x); D2[1] *= __expf(R[2].y);
        D2[2] *= __expf(R[2].z); D2[3] *= __expf(R[2].w);
    };

#pragma unroll
    for (int d = 0; d < DEPTH; ++d) emload(d, 1 + d);

    int s = 1;
    for (;;) {
#pragma unroll
        for (int d = 0; d < DEPTH; ++d) {
            dostep(r[d]);
            if (s == steps) goto done;
            if ((s & (RP - 1)) == 0) {
                float Sx = ((D0[0] + D0[1]) + (D0[2] + D0[3])) +
                           ((D1[0] + D1[1]) + (D1[2] + D1[3])) +
                           ((D2[0] + D2[1]) + (D2[2] + D2[3]));
                Sx += __shfl_xor(Sx, 16, 64);
                Sx += __shfl_xor(Sx, 32, 64);
                int e = (__builtin_bit_cast(int, Sx) >> 23) - 127;
                float scl = __builtin_bit_cast(float, (127 - e) << 23);
                Cexp += e;
                D0 *= scl; D1 *= scl; D2 *= scl;
            }
            {   // repack D -> next B (σ-layout identity)
                i4v nb0 = {pk_bf16(D0[0], D0[1]), pk_bf16(D0[2], D0[3]),
                           pk_bf16(D1[0], D1[1]), pk_bf16(D1[2], D1[3])};
                i4v nb1 = {pk_bf16(D2[0], D2[1]), pk_bf16(D2[2], D2[3]), 0, 0};
                B0 = __builtin_bit_cast(s8v, nb0);
                B1 = __builtin_bit_cast(s8v, nb1);
            }
            emload(d, s + DEPTH);
            ++s;
        }
    }
done:;
    float S = ((D0[0] + D0[1]) + (D0[2] + D0[3])) +
              ((D1[0] + D1[1]) + (D1[2] + D1[3])) +
              ((D2[0] + D2[1]) + (D2[2] + D2[3]));
    S += __shfl_xor(S, 16, 64);
    S += __shfl_xor(S, 32, 64);
    return __logf(S) + (float)Cexp * 0.6931471805599453f;
}

// Length-1 sequences: log-denominator = logsumexp of the single emission row.
__device__ __forceinline__ float den0(const float* __restrict__ rowbase) {
    const int lane = threadIdx.x & 63;
    const int quad = lane >> 4;
    const float* p0 = rowbase + quad * 4;
    float4 ua = *(const float4*)(p0);
    float4 ub = *(const float4*)(p0 + 16);
    float4 uc = *(const float4*)(p0 + 32);
    float S = (__expf(ua.x) + __expf(ua.y) + __expf(ua.z) + __expf(ua.w)) +
              (__expf(ub.x) + __expf(ub.y) + __expf(ub.z) + __expf(ub.w)) +
              (__expf(uc.x) + __expf(uc.y) + __expf(uc.z) + __expf(uc.w));
    S += __shfl_xor(S, 16, 64);
    S += __shfl_xor(S, 32, 64);
    return __logf(S);
}

__global__ void zero_out(float* out) {
    if (threadIdx.x < 3) out[threadIdx.x] = 0.f;
}

// Wave-level role assignment (T spread across 64 blocks -> 64 CUs):
//   bid <  64, widx==0 : T wave, p = bid>>2, b0 = (bid&3)*16   (64 waves)
//   bid <  64, widx>=1 : L wave, w = bid*3 + widx-1            (192 waves)
//   bid >= 64          : lr = 192 + (bid-64)*4 + widx; lr<2048 -> L(w=lr),
//                        else R(w=lr-2048)                     (3904 waves)
__global__ __launch_bounds__(256) void crf_all(const float* __restrict__ logits,
                                               const float* __restrict__ transT,
                                               const float* __restrict__ transL,
                                               const float* __restrict__ transR,
                                               const int* __restrict__ tags,
                                               float* __restrict__ out) {
    __shared__ float s_trans[3][NN * NN];
    const int tid = threadIdx.x, bid = blockIdx.x;
    const int lane = tid & 63, widx = tid >> 6;
    const int quad = lane >> 4;

    for (int i = tid; i < 3 * NN * NN; i += 256)
        s_trans[0][i] = (i < NN * NN) ? transT[i]
                      : (i < 2 * NN * NN) ? transL[i - NN * NN]
                                          : transR[i - 2 * NN * NN];
    __syncthreads();

    // per-wave role
    int role, w = 0;  // w: sequence-group index for L/R
    if (bid < 64) {
        if (widx == 0) { role = 0; }
        else { role = 1; w = bid * 3 + (widx - 1); }
    } else {
        int lr = 192 + (bid - 64) * 4 + widx;
        if (lr < 2048) { role = 1; w = lr; }
        else { role = 2; w = lr - 2048; }
    }
    const float* st = s_trans[role];

    // ---- build σ-permuted Eᵀ A-frags: A[m][k] = exp(trans[σ(k)][t*16+m]) ----
    s8v A[3][2];
    {
        int m = lane & 15;
#pragma unroll
        for (int t = 0; t < 3; ++t) {
            int col = t * 16 + m;
            i4v v0 = {pk_bf16(__expf(st[(quad * 4 + 0) * NN + col]),
                              __expf(st[(quad * 4 + 1) * NN + col])),
                      pk_bf16(__expf(st[(quad * 4 + 2) * NN + col]),
                              __expf(st[(quad * 4 + 3) * NN + col])),
                      pk_bf16(__expf(st[(16 + quad * 4 + 0) * NN + col]),
                              __expf(st[(16 + quad * 4 + 1) * NN + col])),
                      pk_bf16(__expf(st[(16 + quad * 4 + 2) * NN + col]),
                              __expf(st[(16 + quad * 4 + 3) * NN + col]))};
            i4v v1 = {pk_bf16(__expf(st[(32 + quad * 4 + 0) * NN + col]),
                              __expf(st[(32 + quad * 4 + 1) * NN + col])),
                      pk_bf16(__expf(st[(32 + quad * 4 + 2) * NN + col]),
                              __expf(st[(32 + quad * 4 + 3) * NN + col])),
                      0, 0};
            A[t][0] = __builtin_bit_cast(s8v, v0);
            A[t][1] = __builtin_bit_cast(s8v, v1);
        }
    }

    const int seq = lane & 15;
    float ld = 0.f, sc = 0.f;
    if (role == 0) {
        // ---- T: p = bid>>2, b0 = (bid&3)*16; length 512-p
        int p = bid >> 2, b0 = (bid & 3) * 16;
        int steps = (TT - 1) - p;
        const float* rowbase = logits + (size_t)(p * BB + b0 + seq) * (TT * NN);
        ld = den16<4, 8>(rowbase, NN, steps, A);
        // numerator: lanes = (seq sq, time-phase tc)
        int sq = lane >> 2, tc = lane & 3;
        int Ls = TT - p;
        const float* lgs = logits + (size_t)(p * BB + b0 + sq) * (TT * NN);
        const int* tgs = tags + (size_t)(p * BB + b0 + sq) * TT;
        for (int t = tc; t < Ls; t += 4) {
            int tg = tgs[t];
            float e = lgs[t * NN + tg];
            float tsc = (t >= 1) ? st[tgs[t - 1] * NN + tg] : 0.f;
            sc += e + tsc;
        }
    } else if (role == 1) {
        // ---- L: t = w>>2, b0 = (w&3)*16; length min(512-t,16)
        int t = w >> 2, b0 = (w & 3) * 16;
        int Lh = min(TT - t, PP), steps = Lh - 1;
        const float* rowbase = logits + (size_t)(b0 + seq) * (TT * NN) + t * NN;
        if (steps > 0) ld = den16<8, 8>(rowbase, BB * TT * NN, steps, A);
        else ld = den0(rowbase);
        int sq = lane >> 2, pc = lane & 3;
        int bq = b0 + sq;
        for (int p2 = pc; p2 < Lh; p2 += 4) {
            int idx = (p2 * BB + bq) * TT + t;
            int tg = tags[idx];
            sc += logits[(size_t)idx * NN + tg];
            if (p2 >= 1) sc += st[tags[idx - BB * TT] * NN + tg];
        }
    } else {
        // ---- R: t = w>>2; length min(t+1,16); element p at logits[p,b,t-p]
        int t = w >> 2, b0 = (w & 3) * 16;
        int Lh = min(t + 1, PP), steps = Lh - 1;
        const float* rowbase = logits + (size_t)(b0 + seq) * (TT * NN) + t * NN;
        if (steps > 0) ld = den16<8, 8>(rowbase, BB * TT * NN - NN, steps, A);
        else ld = den0(rowbase);
        int sq = lane >> 2, pc = lane & 3;
        int bq = b0 + sq;
        for (int p2 = pc; p2 < Lh; p2 += 4) {
            int idx = (p2 * BB + bq) * TT + (t - p2);
            int tg = tags[idx];
            sc += logits[(size_t)idx * NN + tg];
            if (p2 >= 1) sc += st[tags[((p2 - 1) * BB + bq) * TT + (t - p2 + 1)] * NN + tg];
        }
    }

    // ld is replicated across the 4 quads of each seq — count quad 0 only
    float contrib = ((quad == 0) ? ld : 0.f) - sc;
    contrib = wsum(contrib);
    if (lane == 0) atomicAdd(&out[role], contrib);
}

extern "C" void kernel_launch(void* const* d_in, const int* in_sizes, int n_in,
                              void* d_out, int out_size, void* d_ws, size_t ws_size,
                              hipStream_t stream) {
    const float* logits = (const float*)d_in[0];
    const float* trans_T = (const float*)d_in[1];
    const float* trans_L = (const float*)d_in[2];
    const float* trans_R = (const float*)d_in[3];
    const int* tags = (const int*)d_in[4];
    float* out = (float*)d_out;

    hipLaunchKernelGGL(zero_out, dim3(1), dim3(64), 0, stream, out);
    hipLaunchKernelGGL(crf_all, dim3(1040), dim3(256), 0, stream,
                       logits, trans_T, trans_L, trans_R, tags, out);
}

// Round 8
// 332.559 us; speedup vs baseline: 1.5318x; 1.1634x over previous
//
#include <hip/hip_runtime.h>

#define BB 64
#define TT 512
#define NN 48
#define PP 16

typedef float f4 __attribute__((ext_vector_type(4)));
typedef short s8v __attribute__((ext_vector_type(8)));
typedef int i4v __attribute__((ext_vector_type(4)));

#define LN2 0.6931471805599453f

// bf16 round-to-nearest-even, manual (avoids __hip_bfloat162 bit_cast issues)
__device__ __forceinline__ unsigned f2bf_bits(float x) {
    unsigned u = __builtin_bit_cast(unsigned, x);
    return (u + 0x7fffu + ((u >> 16) & 1u)) >> 16;
}
__device__ __forceinline__ int pk_bf16(float a, float b) {
    return (int)(f2bf_bits(a) | (f2bf_bits(b) << 16));
}
__device__ __forceinline__ float wsum(float v) {
#pragma unroll
    for (int k = 32; k >= 1; k >>= 1) v += __shfl_xor(v, k, 64);
    return v;
}

#define MFMA(A_, B_, C_) __builtin_amdgcn_mfma_f32_16x16x32_bf16(A_, B_, C_, 0, 0, 0)

#define RESCALE(CNT)                                                         \
    do {                                                                     \
        float Sx = ((D0[0] + D0[1]) + (D0[2] + D0[3])) +                     \
                   ((D1[0] + D1[1]) + (D1[2] + D1[3])) +                     \
                   ((D2[0] + D2[1]) + (D2[2] + D2[3]));                      \
        Sx += __shfl_xor(Sx, 16, 64);                                        \
        Sx += __shfl_xor(Sx, 32, 64);                                        \
        int e_ = (__builtin_bit_cast(int, Sx) >> 23) - 127;                  \
        float scl_ = __builtin_bit_cast(float, (127 - e_) << 23);            \
        CNT += e_;                                                           \
        D0 *= scl_; D1 *= scl_; D2 *= scl_;                                  \
    } while (0)

// ---------------------------------------------------------------------------
// Forward chain: alpha' = exp(em) ⊙ (Eᵀ alpha), 16 seqs/wave (seq = lane&15).
// σ-permuted K axis so the D fragment packs DIRECTLY into the next B fragment.
// Exits with D = alpha (after row `steps`'s emission multiply), Cexp = pow2
// exponent pulled out by periodic exact rescaling (period RP).
// ---------------------------------------------------------------------------
template <int RP, int DEPTH>
__device__ __forceinline__ void fwd_chain(const float* __restrict__ p0, int estride,
                                          int steps, const s8v (&A)[3][2],
                                          f4& D0, f4& D1, f4& D2, int& Cexp) {
    const f4 Z = {0.f, 0.f, 0.f, 0.f};
    float4 ua = *(const float4*)(p0);
    float4 ub = *(const float4*)(p0 + 16);
    float4 uc = *(const float4*)(p0 + 32);
    i4v b0i = {pk_bf16(__expf(ua.x), __expf(ua.y)), pk_bf16(__expf(ua.z), __expf(ua.w)),
               pk_bf16(__expf(ub.x), __expf(ub.y)), pk_bf16(__expf(ub.z), __expf(ub.w))};
    i4v b1i = {pk_bf16(__expf(uc.x), __expf(uc.y)), pk_bf16(__expf(uc.z), __expf(uc.w)), 0, 0};
    s8v B0 = __builtin_bit_cast(s8v, b0i);
    s8v B1 = __builtin_bit_cast(s8v, b1i);

    float4 r[DEPTH][3];
    auto emload = [&](int d, int S) {
        int cl = S < steps ? S : steps;
        const float* q = p0 + (size_t)cl * (size_t)estride;
        r[d][0] = *(const float4*)q;
        r[d][1] = *(const float4*)(q + 16);
        r[d][2] = *(const float4*)(q + 32);
    };
#pragma unroll
    for (int d = 0; d < DEPTH; ++d) emload(d, 1 + d);

    int s = 1;
    for (;;) {
#pragma unroll
        for (int d = 0; d < DEPTH; ++d) {
            D0 = MFMA(A[0][1], B1, Z); D0 = MFMA(A[0][0], B0, D0);
            D1 = MFMA(A[1][1], B1, Z); D1 = MFMA(A[1][0], B0, D1);
            D2 = MFMA(A[2][1], B1, Z); D2 = MFMA(A[2][0], B0, D2);
            D0[0] *= __expf(r[d][0].x); D0[1] *= __expf(r[d][0].y);
            D0[2] *= __expf(r[d][0].z); D0[3] *= __expf(r[d][0].w);
            D1[0] *= __expf(r[d][1].x); D1[1] *= __expf(r[d][1].y);
            D1[2] *= __expf(r[d][1].z); D1[3] *= __expf(r[d][1].w);
            D2[0] *= __expf(r[d][2].x); D2[1] *= __expf(r[d][2].y);
            D2[2] *= __expf(r[d][2].z); D2[3] *= __expf(r[d][2].w);
            if (s == steps) return;
            if ((s & (RP - 1)) == 0) RESCALE(Cexp);
            i4v nb0 = {pk_bf16(D0[0], D0[1]), pk_bf16(D0[2], D0[3]),
                       pk_bf16(D1[0], D1[1]), pk_bf16(D1[2], D1[3])};
            i4v nb1 = {pk_bf16(D2[0], D2[1]), pk_bf16(D2[2], D2[3]), 0, 0};
            B0 = __builtin_bit_cast(s8v, nb0);
            B1 = __builtin_bit_cast(s8v, nb1);
            emload(d, s + DEPTH);
            ++s;
        }
    }
}

// ---------------------------------------------------------------------------
// Backward chain: beta' = E·(beta ⊙ exp(em)), consuming rows hi, hi-1, ...
// (nb rows). Init beta = 1. Exits with D = beta (after last MFMA).
// A must be the E-orientation (not Eᵀ): A[m][k] = exp(trans[t*16+m][σ(k)]).
// ---------------------------------------------------------------------------
template <int RP, int DEPTH>
__device__ __forceinline__ void bwd_chain(const float* __restrict__ p0, int estride,
                                          int hi, int nb, const s8v (&A)[3][2],
                                          f4& D0, f4& D1, f4& D2, int& Cexp) {
    const f4 Z = {0.f, 0.f, 0.f, 0.f};
    D0 = f4{1.f, 1.f, 1.f, 1.f}; D1 = D0; D2 = D0;

    float4 r[DEPTH][3];
    auto emload = [&](int d, int ROW) {
        int cl = ROW > 0 ? ROW : 0;
        const float* q = p0 + (size_t)cl * (size_t)estride;
        r[d][0] = *(const float4*)q;
        r[d][1] = *(const float4*)(q + 16);
        r[d][2] = *(const float4*)(q + 32);
    };
#pragma unroll
    for (int d = 0; d < DEPTH; ++d) emload(d, hi - d);

    int j = 1;
    for (;;) {
#pragma unroll
        for (int d = 0; d < DEPTH; ++d) {
            D0[0] *= __expf(r[d][0].x); D0[1] *= __expf(r[d][0].y);
            D0[2] *= __expf(r[d][0].z); D0[3] *= __expf(r[d][0].w);
            D1[0] *= __expf(r[d][1].x); D1[1] *= __expf(r[d][1].y);
            D1[2] *= __expf(r[d][1].z); D1[3] *= __expf(r[d][1].w);
            D2[0] *= __expf(r[d][2].x); D2[1] *= __expf(r[d][2].y);
            D2[2] *= __expf(r[d][2].z); D2[3] *= __expf(r[d][2].w);
            i4v nb0 = {pk_bf16(D0[0], D0[1]), pk_bf16(D0[2], D0[3]),
                       pk_bf16(D1[0], D1[1]), pk_bf16(D1[2], D1[3])};
            i4v nb1 = {pk_bf16(D2[0], D2[1]), pk_bf16(D2[2], D2[3]), 0, 0};
            s8v B0 = __builtin_bit_cast(s8v, nb0);
            s8v B1 = __builtin_bit_cast(s8v, nb1);
            D0 = MFMA(A[0][1], B1, Z); D0 = MFMA(A[0][0], B0, D0);
            D1 = MFMA(A[1][1], B1, Z); D1 = MFMA(A[1][0], B0, D1);
            D2 = MFMA(A[2][1], B1, Z); D2 = MFMA(A[2][0], B0, D2);
            if (j == nb) return;
            if ((j & (RP - 1)) == 0) RESCALE(Cexp);
            emload(d, hi - j - DEPTH + 1);
            ++j;
        }
    }
}

// L/R denominator = fwd chain + final logsum
template <int RP, int DEPTH>
__device__ __forceinline__ float den16(const float* __restrict__ p0, int estride,
                                       int steps, const s8v (&A)[3][2]) {
    f4 D0, D1, D2;
    int Cexp = 0;
    fwd_chain<RP, DEPTH>(p0, estride, steps, A, D0, D1, D2, Cexp);
    float S = ((D0[0] + D0[1]) + (D0[2] + D0[3])) +
              ((D1[0] + D1[1]) + (D1[2] + D1[3])) +
              ((D2[0] + D2[1]) + (D2[2] + D2[3]));
    S += __shfl_xor(S, 16, 64);
    S += __shfl_xor(S, 32, 64);
    return __logf(S) + (float)Cexp * LN2;
}

// Length-1 sequences: logsumexp of the single emission row.
__device__ __forceinline__ float den0(const float* __restrict__ p0) {
    float4 ua = *(const float4*)(p0);
    float4 ub = *(const float4*)(p0 + 16);
    float4 uc = *(const float4*)(p0 + 32);
    float S = (__expf(ua.x) + __expf(ua.y) + __expf(ua.z) + __expf(ua.w)) +
              (__expf(ub.x) + __expf(ub.y) + __expf(ub.z) + __expf(ub.w)) +
              (__expf(uc.x) + __expf(uc.y) + __expf(uc.z) + __expf(uc.w));
    S += __shfl_xor(S, 16, 64);
    S += __shfl_xor(S, 32, 64);
    return __logf(S);
}

// A-frags, forward orientation: A[m][k] = exp(trans[σ(k)][t*16+m])  (Eᵀ·u)
__device__ __forceinline__ void build_A_fwd(const float* __restrict__ st, s8v (&A)[3][2]) {
    int lane = threadIdx.x & 63, m = lane & 15, quad = lane >> 4;
#pragma unroll
    for (int t = 0; t < 3; ++t) {
        int col = t * 16 + m;
        i4v v0 = {pk_bf16(__expf(st[(quad * 4 + 0) * NN + col]), __expf(st[(quad * 4 + 1) * NN + col])),
                  pk_bf16(__expf(st[(quad * 4 + 2) * NN + col]), __expf(st[(quad * 4 + 3) * NN + col])),
                  pk_bf16(__expf(st[(16 + quad * 4 + 0) * NN + col]), __expf(st[(16 + quad * 4 + 1) * NN + col])),
                  pk_bf16(__expf(st[(16 + quad * 4 + 2) * NN + col]), __expf(st[(16 + quad * 4 + 3) * NN + col]))};
        i4v v1 = {pk_bf16(__expf(st[(32 + quad * 4 + 0) * NN + col]), __expf(st[(32 + quad * 4 + 1) * NN + col])),
                  pk_bf16(__expf(st[(32 + quad * 4 + 2) * NN + col]), __expf(st[(32 + quad * 4 + 3) * NN + col])),
                  0, 0};
        A[t][0] = __builtin_bit_cast(s8v, v0);
        A[t][1] = __builtin_bit_cast(s8v, v1);
    }
}

// A-frags, backward orientation: A[m][k] = exp(trans[t*16+m][σ(k)])  (E·x)
__device__ __forceinline__ void build_A_bwd(const float* __restrict__ st, s8v (&A)[3][2]) {
    int lane = threadIdx.x & 63, m = lane & 15, quad = lane >> 4;
#pragma unroll
    for (int t = 0; t < 3; ++t) {
        const float* row = st + (t * 16 + m) * NN;
        i4v v0 = {pk_bf16(__expf(row[quad * 4 + 0]), __expf(row[quad * 4 + 1])),
                  pk_bf16(__expf(row[quad * 4 + 2]), __expf(row[quad * 4 + 3])),
                  pk_bf16(__expf(row[16 + quad * 4 + 0]), __expf(row[16 + quad * 4 + 1])),
                  pk_bf16(__expf(row[16 + quad * 4 + 2]), __expf(row[16 + quad * 4 + 3]))};
        i4v v1 = {pk_bf16(__expf(row[32 + quad * 4 + 0]), __expf(row[32 + quad * 4 + 1])),
                  pk_bf16(__expf(row[32 + quad * 4 + 2]), __expf(row[32 + quad * 4 + 3])),
                  0, 0};
        A[t][0] = __builtin_bit_cast(s8v, v0);
        A[t][1] = __builtin_bit_cast(s8v, v1);
    }
}

// dump D-layout vector (states t*16+quad*4+r, col=seq) + per-seq exponent
__device__ __forceinline__ void dumpD(float* __restrict__ dst, int* __restrict__ cdst,
                                      int g, f4 D0, f4 D1, f4 D2, int Cexp) {
    int lane = threadIdx.x & 63, seq = lane & 15, quad = lane >> 4;
    float* b = dst + (size_t)(g * 16 + seq) * 48 + quad * 4;
#pragma unroll
    for (int r = 0; r < 4; ++r) {
        b[0 * 16 + r] = D0[r];
        b[1 * 16 + r] = D1[r];
        b[2 * 16 + r] = D2[r];
    }
    if (quad == 0) cdst[g * 16 + seq] = Cexp;
}

__global__ void zero_out(float* out) {
    if (threadIdx.x < 3) out[threadIdx.x] = 0.f;
}

// ws layout: alpha[64][16][48] fp32 | beta[64][16][48] fp32 | cf[1024] i32 | cb[1024] i32
#define WS_BETA (64 * 16 * 48)
#define WS_C (2 * 64 * 16 * 48)

// Roles: bid<64: w0=T-fwd(g=bid), w1-3=L | bid<128: w0=T-bwd(g=bid-64), w1-3=L
//        bid<192: all 4 waves = T-numerator(g=bid-128, phase widx)
//        bid>=192: idx<1664 -> L(w=384+idx) else R(w=idx-1664)
__global__ __launch_bounds__(256, 2) void crf_all(const float* __restrict__ logits,
                                                  const float* __restrict__ transT,
                                                  const float* __restrict__ transL,
                                                  const float* __restrict__ transR,
                                                  const int* __restrict__ tags,
                                                  float* __restrict__ out,
                                                  float* __restrict__ ws) {
    __shared__ float s_trans[3][NN * NN];
    const int tid = threadIdx.x, bid = blockIdx.x;
    const int lane = tid & 63, widx = tid >> 6;
    const int quad = lane >> 4, seq = lane & 15;

    for (int i = tid; i < 3 * NN * NN; i += 256)
        s_trans[0][i] = (i < NN * NN) ? transT[i]
                      : (i < 2 * NN * NN) ? transL[i - NN * NN]
                                          : transR[i - 2 * NN * NN];
    __syncthreads();

    // role: 0=Tfwd 1=Tbwd 2=Tnum 3=L 4=R
    int role, w = 0, g = 0;
    if (bid < 64) {
        if (widx == 0) { role = 0; g = bid; }
        else { role = 3; w = bid * 3 + (widx - 1); }
    } else if (bid < 128) {
        if (widx == 0) { role = 1; g = bid - 64; }
        else { role = 3; w = 192 + (bid - 64) * 3 + (widx - 1); }
    } else if (bid < 192) {
        role = 2; g = bid - 128;
    } else {
        int idx = (bid - 192) * 4 + widx;
        if (idx < 1664) { role = 3; w = 384 + idx; }
        else { role = 4; w = idx - 1664; }
    }
    const float* st = (role <= 2) ? s_trans[0] : (role == 3) ? s_trans[1] : s_trans[2];

    s8v A[3][2];
    if (role == 1) build_A_bwd(st, A);
    else if (role != 2) build_A_fwd(st, A);

    if (role == 0 || role == 1) {
        // ---- T chain halves: p = g>>2, b0 = (g&3)*16, total steps = 511-p
        int p = g >> 2, b0 = (g & 3) * 16;
        int steps = (TT - 1) - p;
        int m = steps >> 1, nb = steps - m;
        const float* p0 = logits + (size_t)(p * BB + b0 + seq) * (TT * NN) + quad * 4;
        f4 D0, D1, D2;
        int Cexp = 0;
        int* cf = (int*)(ws + WS_C);
        if (role == 0) {
            fwd_chain<4, 8>(p0, NN, m, A, D0, D1, D2, Cexp);
            dumpD(ws, cf, g, D0, D1, D2, Cexp);
        } else {
            bwd_chain<4, 8>(p0, NN, steps, nb, A, D0, D1, D2, Cexp);
            dumpD(ws + WS_BETA, cf + 1024, g, D0, D1, D2, Cexp);
        }
        return;
    }

    float contrib = 0.f;
    if (role == 2) {
        // ---- T numerator: group g, phase widx; lanes = (seq sq, t-phase)
        int p = g >> 2, b0 = (g & 3) * 16;
        int Ls = TT - p;
        int sq = lane >> 2;
        int t0 = widx * 4 + (lane & 3);
        const float* lgs = logits + (size_t)(p * BB + b0 + sq) * (TT * NN);
        const int* tgs = tags + (size_t)(p * BB + b0 + sq) * TT;
        float sc = 0.f;
        for (int t = t0; t < Ls; t += 16) {
            int tg = tgs[t];
            float e = lgs[t * NN + tg];
            float tsc = (t >= 1) ? st[tgs[t - 1] * NN + tg] : 0.f;
            sc += e + tsc;
        }
        contrib = -sc;
    } else if (role == 3) {
        // ---- L: t = w>>2, b0 = (w&3)*16; length min(512-t,16)
        int t = w >> 2, b0 = (w & 3) * 16;
        int Lh = min(TT - t, PP), steps = Lh - 1;
        const float* p0 = logits + (size_t)(b0 + seq) * (TT * NN) + t * NN + quad * 4;
        float ld = (steps > 0) ? den16<8, 8>(p0, BB * TT * NN, steps, A) : den0(p0);
        float sc = 0.f;
        int sq = lane >> 2, pc = lane & 3;
        int bq = b0 + sq;
        for (int p2 = pc; p2 < Lh; p2 += 4) {
            int idx = (p2 * BB + bq) * TT + t;
            int tg = tags[idx];
            sc += logits[(size_t)idx * NN + tg];
            if (p2 >= 1) sc += st[tags[idx - BB * TT] * NN + tg];
        }
        contrib = ((quad == 0) ? ld : 0.f) - sc;
    } else {
        // ---- R: t = w>>2; length min(t+1,16); element p at logits[p,b,t-p]
        int t = w >> 2, b0 = (w & 3) * 16;
        int Lh = min(t + 1, PP), steps = Lh - 1;
        const float* p0 = logits + (size_t)(b0 + seq) * (TT * NN) + t * NN + quad * 4;
        float ld = (steps > 0) ? den16<8, 8>(p0, BB * TT * NN - NN, steps, A) : den0(p0);
        float sc = 0.f;
        int sq = lane >> 2, pc = lane & 3;
        int bq = b0 + sq;
        for (int p2 = pc; p2 < Lh; p2 += 4) {
            int idx = (p2 * BB + bq) * TT + (t - p2);
            int tg = tags[idx];
            sc += logits[(size_t)idx * NN + tg];
            if (p2 >= 1) sc += st[tags[((p2 - 1) * BB + bq) * TT + (t - p2 + 1)] * NN + tg];
        }
        contrib = ((quad == 0) ? ld : 0.f) - sc;
    }

    contrib = wsum(contrib);
    int oi = (role == 2) ? 0 : (role == 3) ? 1 : 2;
    if (lane == 0) atomicAdd(&out[oi], contrib);
}

// Combine T halves: log Z = log(Σ_s alpha*beta) + ln2*(cf+cb); out[0] += Σ log Z
__global__ __launch_bounds__(256) void t_combine(const float* __restrict__ ws,
                                                 float* __restrict__ out) {
    const int tid = threadIdx.x;
    const float* a = ws;
    const float* b = ws + WS_BETA;
    const int* cf = (const int*)(ws + WS_C);
    const int* cb = cf + 1024;
    float acc = 0.f;
#pragma unroll
    for (int i = 0; i < 4; ++i) {
        int idx = tid * 4 + i;  // 0..1023 = g*16 + seq
        const float* ap = a + idx * 48;
        const float* bp = b + idx * 48;
        float Zv = 0.f;
#pragma unroll
        for (int s = 0; s < 48; ++s) Zv += ap[s] * bp[s];
        acc += __logf(Zv) + LN2 * (float)(cf[idx] + cb[idx]);
    }
    acc = wsum(acc);
    if ((tid & 63) == 0) atomicAdd(&out[0], acc);
}

extern "C" void kernel_launch(void* const* d_in, const int* in_sizes, int n_in,
                              void* d_out, int out_size, void* d_ws, size_t ws_size,
                              hipStream_t stream) {
    const float* logits = (const float*)d_in[0];
    const float* trans_T = (const float*)d_in[1];
    const float* trans_L = (const float*)d_in[2];
    const float* trans_R = (const float*)d_in[3];
    const int* tags = (const int*)d_in[4];
    float* out = (float*)d_out;
    float* ws = (float*)d_ws;

    hipLaunchKernelGGL(zero_out, dim3(1), dim3(64), 0, stream, out);
    hipLaunchKernelGGL(crf_all, dim3(1120), dim3(256), 0, stream,
                       logits, trans_T, trans_L, trans_R, tags, out, ws);
    hipLaunchKernelGGL(t_combine, dim3(1), dim3(256), 0, stream, ws, out);
}

// Round 9
// 331.075 us; speedup vs baseline: 1.5386x; 1.0045x over previous
//
#include <hip/hip_runtime.h>

#define BB 64
#define TT 512
#define NN 48
#define PP 16

typedef float f4 __attribute__((ext_vector_type(4)));
typedef short s8v __attribute__((ext_vector_type(8)));
typedef int i4v __attribute__((ext_vector_type(4)));

#define LN2 0.6931471805599453f

__device__ __forceinline__ unsigned f2bf_bits(float x) {
    unsigned u = __builtin_bit_cast(unsigned, x);
    return (u + 0x7fffu + ((u >> 16) & 1u)) >> 16;
}
__device__ __forceinline__ int pk_bf16(float a, float b) {
    return (int)(f2bf_bits(a) | (f2bf_bits(b) << 16));
}
__device__ __forceinline__ float wsum(float v) {
#pragma unroll
    for (int k = 32; k >= 1; k >>= 1) v += __shfl_xor(v, k, 64);
    return v;
}

#define MFMA(A_, B_, C_) __builtin_amdgcn_mfma_f32_16x16x32_bf16(A_, B_, C_, 0, 0, 0)

#define RESCALE(CNT)                                                         \
    do {                                                                     \
        float Sx = ((D0[0] + D0[1]) + (D0[2] + D0[3])) +                     \
                   ((D1[0] + D1[1]) + (D1[2] + D1[3])) +                     \
                   ((D2[0] + D2[1]) + (D2[2] + D2[3]));                      \
        Sx += __shfl_xor(Sx, 16, 64);                                        \
        Sx += __shfl_xor(Sx, 32, 64);                                        \
        int e_ = (__builtin_bit_cast(int, Sx) >> 23) - 127;                  \
        float scl_ = __builtin_bit_cast(float, (127 - e_) << 23);            \
        CNT += e_;                                                           \
        D0 *= scl_; D1 *= scl_; D2 *= scl_;                                  \
    } while (0)

// Forward chain: alpha' = exp(em) ⊙ (Eᵀ alpha); σ-permuted K so D repacks into B.
template <int RP, int DEPTH>
__device__ __forceinline__ void fwd_chain(const float* __restrict__ p0, int estride,
                                          int steps, const s8v (&A)[3][2],
                                          f4& D0, f4& D1, f4& D2, int& Cexp) {
    const f4 Z = {0.f, 0.f, 0.f, 0.f};
    float4 ua = *(const float4*)(p0);
    float4 ub = *(const float4*)(p0 + 16);
    float4 uc = *(const float4*)(p0 + 32);
    i4v b0i = {pk_bf16(__expf(ua.x), __expf(ua.y)), pk_bf16(__expf(ua.z), __expf(ua.w)),
               pk_bf16(__expf(ub.x), __expf(ub.y)), pk_bf16(__expf(ub.z), __expf(ub.w))};
    i4v b1i = {pk_bf16(__expf(uc.x), __expf(uc.y)), pk_bf16(__expf(uc.z), __expf(uc.w)), 0, 0};
    s8v B0 = __builtin_bit_cast(s8v, b0i);
    s8v B1 = __builtin_bit_cast(s8v, b1i);

    float4 r[DEPTH][3];
    auto emload = [&](int d, int S) {
        int cl = S < steps ? S : steps;
        const float* q = p0 + (size_t)cl * (size_t)estride;
        r[d][0] = *(const float4*)q;
        r[d][1] = *(const float4*)(q + 16);
        r[d][2] = *(const float4*)(q + 32);
    };
#pragma unroll
    for (int d = 0; d < DEPTH; ++d) emload(d, 1 + d);

    int s = 1;
    for (;;) {
#pragma unroll
        for (int d = 0; d < DEPTH; ++d) {
            D0 = MFMA(A[0][1], B1, Z); D0 = MFMA(A[0][0], B0, D0);
            D1 = MFMA(A[1][1], B1, Z); D1 = MFMA(A[1][0], B0, D1);
            D2 = MFMA(A[2][1], B1, Z); D2 = MFMA(A[2][0], B0, D2);
            D0[0] *= __expf(r[d][0].x); D0[1] *= __expf(r[d][0].y);
            D0[2] *= __expf(r[d][0].z); D0[3] *= __expf(r[d][0].w);
            D1[0] *= __expf(r[d][1].x); D1[1] *= __expf(r[d][1].y);
            D1[2] *= __expf(r[d][1].z); D1[3] *= __expf(r[d][1].w);
            D2[0] *= __expf(r[d][2].x); D2[1] *= __expf(r[d][2].y);
            D2[2] *= __expf(r[d][2].z); D2[3] *= __expf(r[d][2].w);
            if (s == steps) return;
            if ((s & (RP - 1)) == 0) RESCALE(Cexp);
            i4v nb0 = {pk_bf16(D0[0], D0[1]), pk_bf16(D0[2], D0[3]),
                       pk_bf16(D1[0], D1[1]), pk_bf16(D1[2], D1[3])};
            i4v nb1 = {pk_bf16(D2[0], D2[1]), pk_bf16(D2[2], D2[3]), 0, 0};
            B0 = __builtin_bit_cast(s8v, nb0);
            B1 = __builtin_bit_cast(s8v, nb1);
            emload(d, s + DEPTH);
            ++s;
        }
    }
}

// Backward chain: beta' = E·(beta ⊙ exp(em)), rows hi, hi-1, ... (nb rows).
template <int RP, int DEPTH>
__device__ __forceinline__ void bwd_chain(const float* __restrict__ p0, int estride,
                                          int hi, int nb, const s8v (&A)[3][2],
                                          f4& D0, f4& D1, f4& D2, int& Cexp) {
    const f4 Z = {0.f, 0.f, 0.f, 0.f};
    D0 = f4{1.f, 1.f, 1.f, 1.f}; D1 = D0; D2 = D0;

    float4 r[DEPTH][3];
    auto emload = [&](int d, int ROW) {
        int cl = ROW > 0 ? ROW : 0;
        const float* q = p0 + (size_t)cl * (size_t)estride;
        r[d][0] = *(const float4*)q;
        r[d][1] = *(const float4*)(q + 16);
        r[d][2] = *(const float4*)(q + 32);
    };
#pragma unroll
    for (int d = 0; d < DEPTH; ++d) emload(d, hi - d);

    int j = 1;
    for (;;) {
#pragma unroll
        for (int d = 0; d < DEPTH; ++d) {
            D0[0] *= __expf(r[d][0].x); D0[1] *= __expf(r[d][0].y);
            D0[2] *= __expf(r[d][0].z); D0[3] *= __expf(r[d][0].w);
            D1[0] *= __expf(r[d][1].x); D1[1] *= __expf(r[d][1].y);
            D1[2] *= __expf(r[d][1].z); D1[3] *= __expf(r[d][1].w);
            D2[0] *= __expf(r[d][2].x); D2[1] *= __expf(r[d][2].y);
            D2[2] *= __expf(r[d][2].z); D2[3] *= __expf(r[d][2].w);
            i4v nb0 = {pk_bf16(D0[0], D0[1]), pk_bf16(D0[2], D0[3]),
                       pk_bf16(D1[0], D1[1]), pk_bf16(D1[2], D1[3])};
            i4v nb1 = {pk_bf16(D2[0], D2[1]), pk_bf16(D2[2], D2[3]), 0, 0};
            s8v B0 = __builtin_bit_cast(s8v, nb0);
            s8v B1 = __builtin_bit_cast(s8v, nb1);
            D0 = MFMA(A[0][1], B1, Z); D0 = MFMA(A[0][0], B0, D0);
            D1 = MFMA(A[1][1], B1, Z); D1 = MFMA(A[1][0], B0, D1);
            D2 = MFMA(A[2][1], B1, Z); D2 = MFMA(A[2][0], B0, D2);
            if (j == nb) return;
            if ((j & (RP - 1)) == 0) RESCALE(Cexp);
            emload(d, hi - j - DEPTH + 1);
            ++j;
        }
    }
}

template <int RP, int DEPTH>
__device__ __forceinline__ float den16(const float* __restrict__ p0, int estride,
                                       int steps, const s8v (&A)[3][2]) {
    f4 D0, D1, D2;
    int Cexp = 0;
    fwd_chain<RP, DEPTH>(p0, estride, steps, A, D0, D1, D2, Cexp);
    float S = ((D0[0] + D0[1]) + (D0[2] + D0[3])) +
              ((D1[0] + D1[1]) + (D1[2] + D1[3])) +
              ((D2[0] + D2[1]) + (D2[2] + D2[3]));
    S += __shfl_xor(S, 16, 64);
    S += __shfl_xor(S, 32, 64);
    return __logf(S) + (float)Cexp * LN2;
}

__device__ __forceinline__ float den0(const float* __restrict__ p0) {
    float4 ua = *(const float4*)(p0);
    float4 ub = *(const float4*)(p0 + 16);
    float4 uc = *(const float4*)(p0 + 32);
    float S = (__expf(ua.x) + __expf(ua.y) + __expf(ua.z) + __expf(ua.w)) +
              (__expf(ub.x) + __expf(ub.y) + __expf(ub.z) + __expf(ub.w)) +
              (__expf(uc.x) + __expf(uc.y) + __expf(uc.z) + __expf(uc.w));
    S += __shfl_xor(S, 16, 64);
    S += __shfl_xor(S, 32, 64);
    return __logf(S);
}

// A-frags fwd: A[m][k] = exp(trans[σ(k)][t*16+m])  (Eᵀ·u)
__device__ __forceinline__ void build_A_fwd(const float* __restrict__ st, s8v (&A)[3][2]) {
    int lane = threadIdx.x & 63, m = lane & 15, quad = lane >> 4;
#pragma unroll
    for (int t = 0; t < 3; ++t) {
        int col = t * 16 + m;
        i4v v0 = {pk_bf16(__expf(st[(quad * 4 + 0) * NN + col]), __expf(st[(quad * 4 + 1) * NN + col])),
                  pk_bf16(__expf(st[(quad * 4 + 2) * NN + col]), __expf(st[(quad * 4 + 3) * NN + col])),
                  pk_bf16(__expf(st[(16 + quad * 4 + 0) * NN + col]), __expf(st[(16 + quad * 4 + 1) * NN + col])),
                  pk_bf16(__expf(st[(16 + quad * 4 + 2) * NN + col]), __expf(st[(16 + quad * 4 + 3) * NN + col]))};
        i4v v1 = {pk_bf16(__expf(st[(32 + quad * 4 + 0) * NN + col]), __expf(st[(32 + quad * 4 + 1) * NN + col])),
                  pk_bf16(__expf(st[(32 + quad * 4 + 2) * NN + col]), __expf(st[(32 + quad * 4 + 3) * NN + col])),
                  0, 0};
        A[t][0] = __builtin_bit_cast(s8v, v0);
        A[t][1] = __builtin_bit_cast(s8v, v1);
    }
}

// A-frags bwd: A[m][k] = exp(trans[t*16+m][σ(k)])  (E·x)
__device__ __forceinline__ void build_A_bwd(const float* __restrict__ st, s8v (&A)[3][2]) {
    int lane = threadIdx.x & 63, m = lane & 15, quad = lane >> 4;
#pragma unroll
    for (int t = 0; t < 3; ++t) {
        const float* row = st + (t * 16 + m) * NN;
        i4v v0 = {pk_bf16(__expf(row[quad * 4 + 0]), __expf(row[quad * 4 + 1])),
                  pk_bf16(__expf(row[quad * 4 + 2]), __expf(row[quad * 4 + 3])),
                  pk_bf16(__expf(row[16 + quad * 4 + 0]), __expf(row[16 + quad * 4 + 1])),
                  pk_bf16(__expf(row[16 + quad * 4 + 2]), __expf(row[16 + quad * 4 + 3]))};
        i4v v1 = {pk_bf16(__expf(row[32 + quad * 4 + 0]), __expf(row[32 + quad * 4 + 1])),
                  pk_bf16(__expf(row[32 + quad * 4 + 2]), __expf(row[32 + quad * 4 + 3])),
                  0, 0};
        A[t][0] = __builtin_bit_cast(s8v, v0);
        A[t][1] = __builtin_bit_cast(s8v, v1);
    }
}

__device__ __forceinline__ void dumpD(float* __restrict__ dst, int* __restrict__ cdst,
                                      int g, f4 D0, f4 D1, f4 D2, int Cexp) {
    int lane = threadIdx.x & 63, seq = lane & 15, quad = lane >> 4;
    float* b = dst + (size_t)(g * 16 + seq) * 48 + quad * 4;
#pragma unroll
    for (int r = 0; r < 4; ++r) {
        b[0 * 16 + r] = D0[r];
        b[1 * 16 + r] = D1[r];
        b[2 * 16 + r] = D2[r];
    }
    if (quad == 0) cdst[g * 16 + seq] = Cexp;
}

__global__ void zero_out(float* out) {
    if (threadIdx.x < 3) out[threadIdx.x] = 0.f;
}

#define WS_BETA (64 * 16 * 48)
#define WS_C (2 * 64 * 16 * 48)

// ---- T-direction chain halves. Own kernel => own (fat) register budget so the
// DEPTH=10 prefetch ring stays resident. 128 blocks x 64 thr: bid<64 fwd, else bwd.
__global__ __launch_bounds__(64, 1) void crf_T(const float* __restrict__ logits,
                                               const float* __restrict__ transT,
                                               float* __restrict__ ws) {
    __shared__ float st[NN * NN];
    const int tid = threadIdx.x, bid = blockIdx.x;
    for (int i = tid; i < NN * NN; i += 64) st[i] = transT[i];
    __syncthreads();

    const int lane = tid & 63, seq = lane & 15, quad = lane >> 4;
    const int dir = bid >> 6, g = bid & 63;
    const int p = g >> 2, b0 = (g & 3) * 16;
    const int steps = (TT - 1) - p;
    const int m = steps >> 1, nb = steps - m;
    const float* p0 = logits + (size_t)(p * BB + b0 + seq) * (TT * NN) + quad * 4;

    s8v A[3][2];
    f4 D0, D1, D2;
    int Cexp = 0;
    int* cf = (int*)(ws + WS_C);
    if (dir == 0) {
        build_A_fwd(st, A);
        fwd_chain<4, 10>(p0, NN, m, A, D0, D1, D2, Cexp);
        dumpD(ws, cf, g, D0, D1, D2, Cexp);
    } else {
        build_A_bwd(st, A);
        bwd_chain<4, 10>(p0, NN, steps, nb, A, D0, D1, D2, Cexp);
        dumpD(ws + WS_BETA, cf + 1024, g, D0, D1, D2, Cexp);
    }
}

// ---- L/R denominators + all numerators. 1088 blocks x 256 thr (4352 waves):
// idx<2048: L(w=idx) | idx<4096: R(w=idx-2048) | else T-numerator (256 waves).
__global__ __launch_bounds__(256) void crf_LR(const float* __restrict__ logits,
                                              const float* __restrict__ transT,
                                              const float* __restrict__ transL,
                                              const float* __restrict__ transR,
                                              const int* __restrict__ tags,
                                              float* __restrict__ out) {
    __shared__ float s_trans[3][NN * NN];
    const int tid = threadIdx.x, bid = blockIdx.x;
    const int lane = tid & 63, widx = tid >> 6;
    const int quad = lane >> 4, seq = lane & 15;

    for (int i = tid; i < 3 * NN * NN; i += 256)
        s_trans[0][i] = (i < NN * NN) ? transT[i]
                      : (i < 2 * NN * NN) ? transL[i - NN * NN]
                                          : transR[i - 2 * NN * NN];
    __syncthreads();

    const int idx = bid * 4 + widx;
    float contrib = 0.f;
    int oi;
    if (idx < 4096) {
        const int isL = idx < 2048;
        const int w = isL ? idx : idx - 2048;
        const float* st = isL ? s_trans[1] : s_trans[2];
        oi = isL ? 1 : 2;
        s8v A[3][2];
        build_A_fwd(st, A);
        int t = w >> 2, b0 = (w & 3) * 16;
        int Lh = isL ? min(TT - t, PP) : min(t + 1, PP);
        int steps = Lh - 1;
        int estride = isL ? BB * TT * NN : BB * TT * NN - NN;
        const float* p0 = logits + (size_t)(b0 + seq) * (TT * NN) + t * NN + quad * 4;
        float ld = (steps > 0) ? den16<8, 8>(p0, estride, steps, A) : den0(p0);
        float sc = 0.f;
        int sq = lane >> 2, pc = lane & 3;
        int bq = b0 + sq;
        if (isL) {
            for (int p2 = pc; p2 < Lh; p2 += 4) {
                int ix = (p2 * BB + bq) * TT + t;
                int tg = tags[ix];
                sc += logits[(size_t)ix * NN + tg];
                if (p2 >= 1) sc += st[tags[ix - BB * TT] * NN + tg];
            }
        } else {
            for (int p2 = pc; p2 < Lh; p2 += 4) {
                int ix = (p2 * BB + bq) * TT + (t - p2);
                int tg = tags[ix];
                sc += logits[(size_t)ix * NN + tg];
                if (p2 >= 1) sc += st[tags[((p2 - 1) * BB + bq) * TT + (t - p2 + 1)] * NN + tg];
            }
        }
        contrib = ((quad == 0) ? ld : 0.f) - sc;
    } else {
        // T numerator: q = idx-4096: g = q>>2, phase = q&3; 16 seqs x 4 t-lanes
        oi = 0;
        int q = idx - 4096;
        int g = q >> 2, phase = q & 3;
        int p = g >> 2, b0 = (g & 3) * 16;
        int Ls = TT - p;
        const float* st = s_trans[0];
        int sq = lane >> 2;
        int t0 = phase * 4 + (lane & 3);
        const float* lgs = logits + (size_t)(p * BB + b0 + sq) * (TT * NN);
        const int* tgs = tags + (size_t)(p * BB + b0 + sq) * TT;
        float sc = 0.f;
        for (int t = t0; t < Ls; t += 16) {
            int tg = tgs[t];
            float e = lgs[t * NN + tg];
            float tsc = (t >= 1) ? st[tgs[t - 1] * NN + tg] : 0.f;
            sc += e + tsc;
        }
        contrib = -sc;
    }

    contrib = wsum(contrib);
    if (lane == 0) atomicAdd(&out[oi], contrib);
}

// Combine T halves: out[0] += Σ_idx [ log(Σ_s alpha*beta) + ln2*(cf+cb) ]
__global__ __launch_bounds__(256) void t_combine(const float* __restrict__ ws,
                                                 float* __restrict__ out) {
    const int idx = blockIdx.x * 256 + threadIdx.x;  // 0..1023
    const float* ap = ws + (size_t)idx * 48;
    const float* bp = ws + WS_BETA + (size_t)idx * 48;
    const int* cf = (const int*)(ws + WS_C);
    const int* cb = cf + 1024;
    float Zv = 0.f;
#pragma unroll
    for (int s = 0; s < 48; ++s) Zv += ap[s] * bp[s];
    float acc = __logf(Zv) + LN2 * (float)(cf[idx] + cb[idx]);
    acc = wsum(acc);
    if ((threadIdx.x & 63) == 0) atomicAdd(&out[0], acc);
}

extern "C" void kernel_launch(void* const* d_in, const int* in_sizes, int n_in,
                              void* d_out, int out_size, void* d_ws, size_t ws_size,
                              hipStream_t stream) {
    const float* logits = (const float*)d_in[0];
    const float* trans_T = (const float*)d_in[1];
    const float* trans_L = (const float*)d_in[2];
    const float* trans_R = (const float*)d_in[3];
    const int* tags = (const int*)d_in[4];
    float* out = (float*)d_out;
    float* ws = (float*)d_ws;

    hipLaunchKernelGGL(zero_out, dim3(1), dim3(64), 0, stream, out);
    hipLaunchKernelGGL(crf_T, dim3(128), dim3(64), 0, stream, logits, trans_T, ws);
    hipLaunchKernelGGL(crf_LR, dim3(1088), dim3(256), 0, stream,
                       logits, trans_T, trans_L, trans_R, tags, out);
    hipLaunchKernelGGL(t_combine, dim3(4), dim3(256), 0, stream, ws, out);
}